// Round 2
// baseline (39297.144 us; speedup 1.0000x reference)
//
#include <hip/hip_runtime.h>
#include <hip/hip_cooperative_groups.h>
#include <stdint.h>
#include <math.h>

// ---------------------------------------------------------------------------
// LSTMAcceptor on MI355X — round 2: persistent cooperative kernel.
//  * Round-1 (per-step launches) = 36 us/step: weights re-fetched every step
//    (24 MB/step, not L2-stable across launches) + launch overhead, at 1
//    wave/SIMD occupancy -> HBM-latency-bound.
//  * Now: ONE cooperative kernel, 256 WGs (1/CU), each WG owns 4 hidden units
//    (16 gate rows). Weight slice (hi/lo split bf16, 96 KB) lives in LDS for
//    the whole sequence; c lives in registers; grid.sync() is the step barrier.
//  * Per-step global traffic: h broadcast (hi/lo, 256 KB/WG) + emb slice
//    (128 KB/WG, pre-gathered+pre-split [t][b][k] so the hot loop does zero
//    split VALU). Fallback to on-the-fly emb split if ws < 68 MB.
//  * Precision: split-bf16 (w_hi*h_hi + w_hi*h_lo + w_lo*h_hi), verified
//    round-1 absmax 2.4e-7.
//  * LDS weight layout is kc-blocked fragment-linear: byte addr = kc*1024 +
//    lane*16 -> conflict-free ds_read_b128.
// ---------------------------------------------------------------------------

#define HID  1024
#define EMBD 512
#define NB   64
#define NT   512
#define G4   4096
#define NWG  256   // gate tiles: 4 hidden units each
#define TPB  256

using bf16x8  = __attribute__((ext_vector_type(8))) __bf16;
using ushort8 = __attribute__((ext_vector_type(8))) unsigned short;
using f32x4   = __attribute__((ext_vector_type(4))) float;

__device__ __forceinline__ unsigned short f2bf(float f) {
  unsigned u = __float_as_uint(f);
  u += 0x7fffu + ((u >> 16) & 1u);
  return (unsigned short)(u >> 16);
}
__device__ __forceinline__ float bf2f(unsigned short s) {
  return __uint_as_float(((unsigned)s) << 16);
}

// ---------------------------------------------------------------------------
__global__ void zero_state(unsigned int* __restrict__ p) {
  p[blockIdx.x * 256 + threadIdx.x] = 0u;  // grid 256x256 covers h0Hi+h0Lo (256 KB)
}

__global__ void prep_bias(const float* __restrict__ bih, const float* __restrict__ bhh,
                          float* __restrict__ bias) {
  int i = blockIdx.x * 256 + threadIdx.x;
  if (i < G4) bias[i] = bih[i] + bhh[i];
}

// gather emb rows per (t,b) and split to hi/lo bf16, layout [t][b][k]
__global__ void prep_emb(const int* __restrict__ x, const float* __restrict__ emb,
                         unsigned short* __restrict__ eHi, unsigned short* __restrict__ eLo) {
  const int bid = blockIdx.x;          // = t*NB + b
  const int b = bid & (NB - 1);
  const int t = bid >> 6;
  const int k = threadIdx.x * 4;       // 128 threads x 4 elems = 512
  const int tok = x[b * NT + t];
  float4 v = {0.f, 0.f, 0.f, 0.f};
  if (tok != 0) v = *(const float4*)(emb + (size_t)tok * EMBD + k);
  float vs[4] = {v.x, v.y, v.z, v.w};
  unsigned short hs[4], ls[4];
#pragma unroll
  for (int i = 0; i < 4; ++i) {
    unsigned short hb = f2bf(vs[i]);
    hs[i] = hb;
    ls[i] = f2bf(vs[i] - bf2f(hb));
  }
  const size_t base = (size_t)bid * EMBD + k;
  *(uint2*)(eHi + base) = make_uint2((unsigned)hs[0] | ((unsigned)hs[1] << 16),
                                     (unsigned)hs[2] | ((unsigned)hs[3] << 16));
  *(uint2*)(eLo + base) = make_uint2((unsigned)ls[0] | ((unsigned)ls[1] << 16),
                                     (unsigned)ls[2] | ((unsigned)ls[3] << 16));
}

// ---------------------------------------------------------------------------
// Persistent LSTM. 256 WGs x 256 threads (4 waves). WG gt owns hidden units
// gt*4..gt*4+3 (gate rows q*HID + gt*4 + j, q=0..3 i/f/g/o). Each wave does a
// 16x16 MFMA tile over 16 batch rows x 16 gate rows, K = 1536 (512 emb +
// 1024 h), split-bf16 (3 MFMA per 32-K chunk).
__global__ __launch_bounds__(TPB, 1) void lstm_persistent(
    const int* __restrict__ x, const float* __restrict__ emb,
    const unsigned short* __restrict__ eHi, const unsigned short* __restrict__ eLo,
    const int embSplit,
    const float* __restrict__ Wih, const float* __restrict__ Whh,
    const float* __restrict__ bias,
    unsigned short* __restrict__ h0Hi, unsigned short* __restrict__ h0Lo,
    unsigned short* __restrict__ h1Hi, unsigned short* __restrict__ h1Lo) {
  extern __shared__ unsigned short wb[];   // wbHi[24576] ++ wbLo[24576] (96 KB dynamic)
  unsigned short* wbHi = wb;
  unsigned short* wbLo = wb + 24576;
  __shared__ float gl[16][68];             // gate exchange [n=16 gate rows][m=64 batch]
  __shared__ unsigned short hst[64][8];    // h repack: [b][hi j0..3 | lo j0..3]

  const int gt   = blockIdx.x;
  const int tid  = threadIdx.x;
  const int lane = tid & 63;
  const int wave = tid >> 6;

  // ---- fill weight LDS once: fragment-linear kc-blocked layout ----
  // elem e -> (kc = e>>9, kg = (e>>7)&3, n = (e>>3)&15, i = e&7), k = kc*32+kg*8+i
  for (int e = tid; e < 24576; e += TPB) {
    const int i = e & 7, n = (e >> 3) & 15, kg = (e >> 7) & 3, kc = e >> 9;
    const int k = kc * 32 + kg * 8 + i;
    const int grow = (n >> 2) * HID + gt * 4 + (n & 3);
    const float v = (k < EMBD) ? Wih[(size_t)grow * EMBD + k]
                               : Whh[(size_t)grow * HID + (k - EMBD)];
    const unsigned short hb = f2bf(v);
    wbHi[e] = hb;
    wbLo[e] = f2bf(v - bf2f(hb));
  }

  // cell-update role: thread -> (batch cb, unit cj); c stays in a register
  const int cb = tid >> 2, cj = tid & 3;
  const int hu = gt * 4 + cj;
  const float bI = bias[hu], bF = bias[HID + hu];
  const float bG = bias[2 * HID + hu], bO = bias[3 * HID + hu];
  float c_reg = 0.f;

  // MFMA fragment role
  const int m15  = lane & 15;        // A row within tile == B col (n)
  const int kg8  = (lane >> 4) * 8;  // k subgroup
  const int mrow = wave * 16 + m15;  // batch row 0..63

  cooperative_groups::grid_group grid = cooperative_groups::this_grid();
  __syncthreads();  // wb ready

  for (int t = 0; t < NT; ++t) {
    const unsigned short* hInHi = (t & 1) ? h1Hi : h0Hi;
    const unsigned short* hInLo = (t & 1) ? h1Lo : h0Lo;
    unsigned short* hOutHi = (t & 1) ? h0Hi : h1Hi;
    unsigned short* hOutLo = (t & 1) ? h0Lo : h1Lo;

    f32x4 acc0 = {0.f, 0.f, 0.f, 0.f}, acc1 = {0.f, 0.f, 0.f, 0.f};

    // ---- input-projection part: K = 0..511 ----
    if (embSplit) {
      const unsigned short* eh = eHi + ((size_t)t * NB + mrow) * EMBD;
      const unsigned short* el = eLo + ((size_t)t * NB + mrow) * EMBD;
#pragma unroll 4
      for (int kc = 0; kc < 16; ++kc) {
        const int k0 = kc * 32 + kg8;
        bf16x8 aH = *(const bf16x8*)(eh + k0);
        bf16x8 aL = *(const bf16x8*)(el + k0);
        bf16x8 bH = *(const bf16x8*)(wbHi + kc * 512 + lane * 8);
        bf16x8 bL = *(const bf16x8*)(wbLo + kc * 512 + lane * 8);
        f32x4& acc = (kc & 1) ? acc1 : acc0;
        acc = __builtin_amdgcn_mfma_f32_16x16x32_bf16(aH, bH, acc, 0, 0, 0);
        acc = __builtin_amdgcn_mfma_f32_16x16x32_bf16(aH, bL, acc, 0, 0, 0);
        acc = __builtin_amdgcn_mfma_f32_16x16x32_bf16(aL, bH, acc, 0, 0, 0);
      }
    } else {
      const int tok = x[mrow * NT + t];
      const float* erow = emb + (size_t)tok * EMBD;
#pragma unroll 2
      for (int kc = 0; kc < 16; ++kc) {
        const int k0 = kc * 32 + kg8;
        float4 f0 = {0.f, 0.f, 0.f, 0.f}, f1 = {0.f, 0.f, 0.f, 0.f};
        if (tok != 0) {
          f0 = *(const float4*)(erow + k0);
          f1 = *(const float4*)(erow + k0 + 4);
        }
        const float vs[8] = {f0.x, f0.y, f0.z, f0.w, f1.x, f1.y, f1.z, f1.w};
        ushort8 ah, al;
#pragma unroll
        for (int i = 0; i < 8; ++i) {
          unsigned short hb = f2bf(vs[i]);
          ah[i] = hb;
          al[i] = f2bf(vs[i] - bf2f(hb));
        }
        bf16x8 aH = __builtin_bit_cast(bf16x8, ah);
        bf16x8 aL = __builtin_bit_cast(bf16x8, al);
        bf16x8 bH = *(const bf16x8*)(wbHi + kc * 512 + lane * 8);
        bf16x8 bL = *(const bf16x8*)(wbLo + kc * 512 + lane * 8);
        f32x4& acc = (kc & 1) ? acc1 : acc0;
        acc = __builtin_amdgcn_mfma_f32_16x16x32_bf16(aH, bH, acc, 0, 0, 0);
        acc = __builtin_amdgcn_mfma_f32_16x16x32_bf16(aH, bL, acc, 0, 0, 0);
        acc = __builtin_amdgcn_mfma_f32_16x16x32_bf16(aL, bH, acc, 0, 0, 0);
      }
    }

    // ---- recurrent part: K = 512..1535 (h pre-split by previous step) ----
    {
      const unsigned short* ah_ = hInHi + (size_t)mrow * HID;
      const unsigned short* al_ = hInLo + (size_t)mrow * HID;
#pragma unroll 4
      for (int kc = 0; kc < 32; ++kc) {
        const int k0 = kc * 32 + kg8;
        bf16x8 aH = *(const bf16x8*)(ah_ + k0);
        bf16x8 aL = *(const bf16x8*)(al_ + k0);
        bf16x8 bH = *(const bf16x8*)(wbHi + (16 + kc) * 512 + lane * 8);
        bf16x8 bL = *(const bf16x8*)(wbLo + (16 + kc) * 512 + lane * 8);
        f32x4& acc = (kc & 1) ? acc1 : acc0;
        acc = __builtin_amdgcn_mfma_f32_16x16x32_bf16(aH, bH, acc, 0, 0, 0);
        acc = __builtin_amdgcn_mfma_f32_16x16x32_bf16(aH, bL, acc, 0, 0, 0);
        acc = __builtin_amdgcn_mfma_f32_16x16x32_bf16(aL, bH, acc, 0, 0, 0);
      }
    }

    // ---- exchange across waves: C/D layout m=(lane>>4)*4+r, n=lane&15 ----
    const int mb = wave * 16 + (lane >> 4) * 4;
#pragma unroll
    for (int r = 0; r < 4; ++r) gl[m15][mb + r] = acc0[r] + acc1[r];
    __syncthreads();

    // ---- cell update (one c per thread, in-register across all 512 steps) --
    const float gi = gl[0 + cj][cb] + bI;
    const float gf = gl[4 + cj][cb] + bF;
    const float gg = gl[8 + cj][cb] + bG;
    const float go = gl[12 + cj][cb] + bO;
    const float si = 1.f / (1.f + expf(-gi));
    const float sf = 1.f / (1.f + expf(-gf));
    const float so = 1.f / (1.f + expf(-go));
    const float tg = tanhf(gg);
    c_reg = sf * c_reg + si * tg;
    const float hn = so * tanhf(c_reg);
    const unsigned short hb = f2bf(hn);
    hst[cb][cj] = hb;
    hst[cb][4 + cj] = f2bf(hn - bf2f(hb));
    __syncthreads();

    // ---- coalesced-ish h writeback: 8B per row (4 units) ----
    if (tid < 64) {
      const unsigned long long v = *(const unsigned long long*)&hst[tid][0];
      *(unsigned long long*)(hOutHi + (size_t)tid * HID + gt * 4) = v;
    } else if (tid < 128) {
      const int b = tid - 64;
      const unsigned long long v = *(const unsigned long long*)&hst[b][4];
      *(unsigned long long*)(hOutLo + (size_t)b * HID + gt * 4) = v;
    }
    __threadfence();   // device-scope release (cross-XCD L2 wb/inv)
    grid.sync();
  }
}

// ---------------------------------------------------------------------------
__global__ __launch_bounds__(256) void head_kernel(
    const unsigned short* __restrict__ hHi, const unsigned short* __restrict__ hLo,
    const float* __restrict__ W1, const float* __restrict__ b1,
    const float* __restrict__ W2, const float* __restrict__ b2,
    float* __restrict__ out) {
  const int b = blockIdx.x;
  const int tid = threadIdx.x;
  const int u = tid >> 2, q = tid & 3;
  const int base = b * HID;

  float s = 0.f;
  const int k0 = q * 256;
#pragma unroll 4
  for (int k = k0; k < k0 + 256; ++k) {
    float hv = bf2f(hHi[base + k]) + bf2f(hLo[base + k]);
    s += W1[u * HID + k] * hv;
  }
  __shared__ float red[64][4];
  __shared__ float hl[64];
  red[u][q] = s;
  __syncthreads();
  if (tid < 64) {
    float v = red[tid][0] + red[tid][1] + red[tid][2] + red[tid][3] + b1[tid];
    hl[tid] = v > 0.f ? v : 0.f;
  }
  __syncthreads();
  if (tid < 64) {
    float v = hl[tid] * W2[tid];
#pragma unroll
    for (int off = 32; off; off >>= 1) v += __shfl_down(v, off);
    if (tid == 0) out[b] = v + b2[0];
  }
}

// ---------------------------------------------------------------------------
extern "C" void kernel_launch(void* const* d_in, const int* in_sizes, int n_in,
                              void* d_out, int out_size, void* d_ws, size_t ws_size,
                              hipStream_t stream) {
  (void)in_sizes; (void)n_in; (void)out_size;
  const int*   x   = (const int*)d_in[0];
  // d_in[1] = lengths : UNUSED by the reference
  const float* emb = (const float*)d_in[2];
  const float* Wih = (const float*)d_in[3];
  const float* bih = (const float*)d_in[4];
  const float* Whh = (const float*)d_in[5];
  const float* bhh = (const float*)d_in[6];
  const float* W1  = (const float*)d_in[7];
  const float* b1  = (const float*)d_in[8];
  const float* W2  = (const float*)d_in[9];
  const float* b2  = (const float*)d_in[10];
  float* out = (float*)d_out;

  // ---- ws layout ----
  char* ws = (char*)d_ws;
  unsigned short* h0Hi = (unsigned short*)(ws);                  // 128 KB
  unsigned short* h0Lo = (unsigned short*)(ws + (128 << 10));    // 128 KB
  unsigned short* h1Hi = (unsigned short*)(ws + (256 << 10));    // 128 KB
  unsigned short* h1Lo = (unsigned short*)(ws + (384 << 10));    // 128 KB
  float*          bias = (float*)(ws + (512 << 10));             // 16 KB
  unsigned short* eHi  = (unsigned short*)(ws + (528 << 10));    // 32 MB
  unsigned short* eLo  = eHi + (size_t)NB * NT * EMBD;           // 32 MB

  const size_t need_min  = (528ull << 10);
  const size_t need_full = need_min + 2ull * ((size_t)NB * NT * EMBD * 2);
  if (ws_size < need_min) return;
  int embSplit = (ws_size >= need_full) ? 1 : 0;

  const unsigned dynLDS = 2u * 24576u * 2u;  // 96 KB (wbHi+wbLo)
  (void)hipFuncSetAttribute((const void*)lstm_persistent,
                            hipFuncAttributeMaxDynamicSharedMemorySize, (int)dynLDS);

  zero_state<<<256, 256, 0, stream>>>((unsigned int*)ws);
  prep_bias<<<16, 256, 0, stream>>>(bih, bhh, bias);
  if (embSplit) prep_emb<<<NB * NT, 128, 0, stream>>>(x, emb, eHi, eLo);

  void* args[] = {(void*)&x, (void*)&emb, (void*)&eHi, (void*)&eLo, (void*)&embSplit,
                  (void*)&Wih, (void*)&Whh, (void*)&bias,
                  (void*)&h0Hi, (void*)&h0Lo, (void*)&h1Hi, (void*)&h1Lo};
  (void)hipLaunchCooperativeKernel((void*)lstm_persistent, dim3(NWG), dim3(TPB),
                                   args, dynLDS, stream);

  // after 512 steps the freshest h is in buffer 0
  head_kernel<<<64, 256, 0, stream>>>(h0Hi, h0Lo, W1, b1, W2, b2, out);
}